// Round 1
// 1041.236 us; speedup vs baseline: 1.0035x; 1.0035x over previous
//
#include <hip/hip_runtime.h>

// ContinuousLearningLayer: pooled[i][j] = any_{k in [j-25, j+25]} (|in[i] - w[k]| < 0.1)
// in: 1024 fp32 (flattened (2,512)), w: 262144 fp32, out: [1024, 262144] fp32 in {0,1}
//
// Fused single kernel, R=4 rows per block (weight loads amortized 4x):
//  Phase 1: float4 weight loads; each thread tests 16 weights against 4 row
//           values, packs four 16-bit predicate groups into LDS.
//  Phase 2: per row, raw 64-bit word = one 8 B LDS read (4 ushorts);
//           radius-25 dilation via 128-bit shift-OR; dilated word to LDS.
//  Phase 3: bit -> fp32 expansion, coalesced 16 B/lane NONTEMPORAL stores
//           (output is write-once; keep it out of L2 so weights stay resident).
// Memory-bound on the 1.07 GB output write (~171 us at fill-rate 6.3 TB/s).

static constexpr int N_ROWS   = 1024;
static constexpr int M_W      = 262144;
static constexpr int CHUNK    = 16384;             // outputs per (row, block)
static constexpr int NWORDS   = CHUNK / 64;        // 256 dilated words per row
static constexpr int NGROUPS  = (NWORDS + 2) * 4;  // 1032 16-bit predicate groups
static constexpr int R        = 4;                 // rows per block
static constexpr float THRESH = 0.1f;

typedef unsigned int u32x4 __attribute__((ext_vector_type(4)));

__global__ __launch_bounds__(256) void cll_fused3_kernel(const float* __restrict__ in,
                                                         const float* __restrict__ wm,
                                                         float* __restrict__ out) {
    // preds[r]: group g covers weights j = chunkBase - 64 + 16*g .. +15 for row r
    __shared__ unsigned short preds[R][NGROUPS];       // 4 x 2064 B (8 B aligned rows)
    __shared__ unsigned long long dil[R][NWORDS];      // 4 x 2048 B

    const int tid = threadIdx.x;
    const int row0 = blockIdx.y * R;
    const int chunkBase = blockIdx.x * CHUNK;

    float x[R];
    #pragma unroll
    for (int r = 0; r < R; ++r) x[r] = in[row0 + r];

    // ---- Phase 1: predicate groups via float4 loads, 4 rows per loaded weight.
    // chunkBase, M_W and the -64 halo are multiples of 16, so each group is
    // either fully in-range or fully out-of-range (OOB -> 0 bits, matching
    // -inf max-pool padding: every window has >=26 valid elements).
    const float4* wm4 = (const float4*)wm;
    #pragma unroll
    for (int it = 0; it < 5; ++it) {
        const int g = it * 256 + tid;
        if (g < NGROUPS) {                          // wave-uniform except it==4
            const int jlo = chunkBase - 64 + g * 16;
            unsigned bits[R];
            #pragma unroll
            for (int r = 0; r < R; ++r) bits[r] = 0;
            if (jlo >= 0 && jlo < M_W) {
                const int f4 = jlo >> 2;            // float4 index
                #pragma unroll
                for (int c = 0; c < 4; ++c) {
                    const float4 v = wm4[f4 + c];
                    #pragma unroll
                    for (int r = 0; r < R; ++r) {
                        bits[r] |= (unsigned)(__builtin_fabsf(v.x - x[r]) < THRESH) << (c * 4 + 0);
                        bits[r] |= (unsigned)(__builtin_fabsf(v.y - x[r]) < THRESH) << (c * 4 + 1);
                        bits[r] |= (unsigned)(__builtin_fabsf(v.z - x[r]) < THRESH) << (c * 4 + 2);
                        bits[r] |= (unsigned)(__builtin_fabsf(v.w - x[r]) < THRESH) << (c * 4 + 3);
                    }
                }
            }
            #pragma unroll
            for (int r = 0; r < R; ++r) preds[r][g] = (unsigned short)bits[r];
        }
    }
    __syncthreads();

    // ---- Phase 2: word build (8 B LDS read: 4 little-endian ushorts == u64)
    // + radius-25 dilation, per row. Raw word w covers j = chunkBase-64+64*w..+63.
    // Dilated word t needs raw words t, t+1, t+2:
    //   y bit q = raw stream bit (t*64 + 39 + q), q in [0,128)
    //   out bit i = OR_{u=0..50} y bit (i+u).
    #pragma unroll
    for (int r = 0; r < R; ++r) {
        const unsigned long long lo  = *(const unsigned long long*)&preds[r][4 * tid];
        const unsigned long long mid = *(const unsigned long long*)&preds[r][4 * tid + 4];
        const unsigned long long hi  = *(const unsigned long long*)&preds[r][4 * tid + 8];
        __uint128_t z = ((__uint128_t)(lo >> 39))
                      | ((__uint128_t)mid << 25)
                      | ((__uint128_t)hi << 89);
        z |= z >> 1;
        z |= z >> 2;
        z |= z >> 4;
        z |= z >> 8;
        z |= z >> 16;
        z |= z >> 19;   // union covers shifts 0..50
        dil[r][tid] = (unsigned long long)z;
    }
    __syncthreads();

    // ---- Phase 3: expand bits -> fp32, coalesced nontemporal uint4 stores
    // (1 KB/wave, write-once stream — bypass L2).
    #pragma unroll
    for (int r = 0; r < R; ++r) {
        u32x4* orow = (u32x4*)(out + (long long)(row0 + r) * M_W + chunkBase);
        #pragma unroll
        for (int it = 0; it < CHUNK / 1024; ++it) {
            const int e = it * 1024 + tid * 4;              // element offset, 4 bits/thread
            const unsigned long long wbits = dil[r][e >> 6]; // 16 lanes broadcast same word
            const unsigned b4 = (unsigned)(wbits >> (e & 63)) & 0xFu;
            u32x4 v;
            v.x = (b4 & 1u) ? 0x3F800000u : 0u;
            v.y = (b4 & 2u) ? 0x3F800000u : 0u;
            v.z = (b4 & 4u) ? 0x3F800000u : 0u;
            v.w = (b4 & 8u) ? 0x3F800000u : 0u;
            __builtin_nontemporal_store(v, &orow[e >> 2]);
        }
    }
}

extern "C" void kernel_launch(void* const* d_in, const int* in_sizes, int n_in,
                              void* d_out, int out_size, void* d_ws, size_t ws_size,
                              hipStream_t stream) {
    const float* in = (const float*)d_in[0];    // input_features (2,512) fp32
    const float* wm = (const float*)d_in[1];    // weight_matrix (512,512) fp32
    float* out = (float*)d_out;

    dim3 grid(M_W / CHUNK, N_ROWS / R);         // (16, 256) = 4096 blocks
    cll_fused3_kernel<<<grid, 256, 0, stream>>>(in, wm, out);
}